// Round 1
// baseline (171.086 us; speedup 1.0000x reference)
//
#include <hip/hip_runtime.h>
#include <hip/hip_bf16.h>
#include <stdint.h>

// Problem constants (B,H,W,C) = (8,128,128,64); out width = (W-1)+H = 255.
#define BB 8
#define HH 128
#define WW 128
#define CC 64
#define OUTW 255

// 128 rows of bf16, padded 64 -> 72 elems (144 B): keeps 16B alignment for
// ds_read_b128 and offsets consecutive rows by 4 banks.
#define LDS_STRIDE 72

typedef __attribute__((ext_vector_type(8))) short bf16x8;   // 8 bf16 in 4 VGPRs
typedef __attribute__((ext_vector_type(4))) float f32x4;

__device__ __forceinline__ unsigned short f2bf(float f) {
    union { float f; uint32_t u; } v; v.f = f;
    uint32_t u = v.u;
    // round-to-nearest-even; inputs are finite normals (no NaN handling needed)
    return (unsigned short)((u + 0x7FFFu + ((u >> 16) & 1u)) >> 16);
}

// One block computes one 128x128 Gram matrix G = X * X^T, X = 128x64.
// Blocks [0, B*H): row grams (pixels of row i). Blocks [B*H, B*H+B*W): col grams.
__global__ __launch_bounds__(256)
void criss_cross_gram_kernel(const float* __restrict__ x, float* __restrict__ out) {
    __shared__ unsigned short lds[128 * LDS_STRIDE];

    const int g = blockIdx.x;
    const bool isCol = (g >= BB * HH);
    const int gg = isCol ? (g - BB * HH) : g;
    const int b = gg >> 7;       // / 128
    const int p = gg & 127;      // i (row gram) or j (col gram)

    const float* xbase;
    int xRowStride;      // floats between consecutive X rows
    int outBase;         // float offset of G-row 0 in out
    int outRowStride;    // floats between consecutive G rows in out
    if (!isCol) {
        xbase        = x + ((b * HH + p) * WW) * CC;   // x[b,p,0,:]
        xRowStride   = CC;                              // row pixels contiguous
        outBase      = ((b * HH + p) * WW) * OUTW;      // out[b,p,j,*]
        outRowStride = OUTW;
    } else {
        xbase        = x + (b * HH * WW + p) * CC;      // x[b,0,p,:]
        xRowStride   = WW * CC;                         // column pixels strided
        outBase      = (b * HH * WW + p) * OUTW;        // out[b,i,p,127+*]
        outRowStride = WW * OUTW;
    }

    const int t = threadIdx.x;

    // ---- Stage X (128x64 fp32) into LDS as bf16. 2048 float4 loads total. ----
    #pragma unroll
    for (int r = 0; r < 8; ++r) {
        const int idx = r * 256 + t;        // 0..2047
        const int row = idx >> 4;           // 0..127
        const int c4  = (idx & 15) << 2;    // float4 column
        const float4 v = *(const float4*)(xbase + row * xRowStride + c4);
        ushort4* dst = (ushort4*)&lds[row * LDS_STRIDE + c4];
        *dst = make_ushort4(f2bf(v.x), f2bf(v.y), f2bf(v.z), f2bf(v.w));
    }
    __syncthreads();

    // ---- MFMA: wave w computes rows [w*32, w*32+32) x all 128 cols. ----
    const int wave = t >> 6;
    const int lane = t & 63;
    const int m16  = lane & 15;
    const int quad = lane >> 4;

    f32x4 acc[2][8];
    #pragma unroll
    for (int rt = 0; rt < 2; ++rt)
        #pragma unroll
        for (int ct = 0; ct < 8; ++ct)
            acc[rt][ct] = (f32x4){0.f, 0.f, 0.f, 0.f};

    #pragma unroll
    for (int ks = 0; ks < 2; ++ks) {
        const int kOff = ks * 32 + quad * 8;
        bf16x8 afrag[2];
        #pragma unroll
        for (int rt = 0; rt < 2; ++rt) {
            const int row = wave * 32 + rt * 16 + m16;
            afrag[rt] = *(const bf16x8*)&lds[row * LDS_STRIDE + kOff];
        }
        #pragma unroll
        for (int ct = 0; ct < 8; ++ct) {
            const int row = ct * 16 + m16;
            const bf16x8 bfrag = *(const bf16x8*)&lds[row * LDS_STRIDE + kOff];
            acc[0][ct] = __builtin_amdgcn_mfma_f32_16x16x32_bf16(afrag[0], bfrag, acc[0][ct], 0, 0, 0);
            acc[1][ct] = __builtin_amdgcn_mfma_f32_16x16x32_bf16(afrag[1], bfrag, acc[1][ct], 0, 0, 0);
        }
    }

    // ---- Store. C/D layout: col = lane&15, row = quad*4 + reg. ----
    #pragma unroll
    for (int rt = 0; rt < 2; ++rt) {
        #pragma unroll
        for (int reg = 0; reg < 4; ++reg) {
            const int gm = wave * 32 + rt * 16 + quad * 4 + reg;
            float* rowp = out + outBase + gm * outRowStride;
            #pragma unroll
            for (int ct = 0; ct < 8; ++ct) {
                const int gn = ct * 16 + m16;
                const float vv = acc[rt][ct][reg];
                if (!isCol) {
                    if (gn != gm) {
                        // skip diagonal, compact: k<j -> k, k>j -> k-1
                        rowp[gn - (gn > gm ? 1 : 0)] = vv;
                    }
                } else {
                    rowp[127 + gn] = vv;
                }
            }
        }
    }
}

extern "C" void kernel_launch(void* const* d_in, const int* in_sizes, int n_in,
                              void* d_out, int out_size, void* d_ws, size_t ws_size,
                              hipStream_t stream) {
    const float* x = (const float*)d_in[0];
    float* out = (float*)d_out;
    // 1024 row-gram blocks + 1024 col-gram blocks, one 128x128 Gram each.
    criss_cross_gram_kernel<<<dim3(BB * HH + BB * WW), dim3(256), 0, stream>>>(x, out);
}

// Round 2
// 169.627 us; speedup vs baseline: 1.0086x; 1.0086x over previous
//
#include <hip/hip_runtime.h>
#include <hip/hip_bf16.h>
#include <stdint.h>

// Problem constants (B,H,W,C) = (8,128,128,64); out width = (W-1)+H = 255.
#define BB 8
#define HH 128
#define WW 128
#define CC 64
#define OUTW 255

// X staging: 128 rows of bf16, padded 64 -> 72 elems (144 B): keeps 16B
// alignment for ds_read_b128 and offsets consecutive rows by 4 banks.
#define LDS_STRIDE 72
// Epilogue staging: 16 rows x 130 floats per wave (130 mod 32 = 2 -> row
// offset 2 banks; C-fragment writes land 2-way aliased = free).
#define EP_STRIDE 130

typedef __attribute__((ext_vector_type(8))) short bf16x8;   // 8 bf16 in 4 VGPRs
typedef __attribute__((ext_vector_type(4))) float f32x4;

__device__ __forceinline__ unsigned short f2bf(float f) {
    union { float f; uint32_t u; } v; v.f = f;
    uint32_t u = v.u;
    // round-to-nearest-even; inputs are finite normals (no NaN handling needed)
    return (unsigned short)((u + 0x7FFFu + ((u >> 16) & 1u)) >> 16);
}

// One block computes one 128x128 Gram matrix G = X * X^T, X = 128x64.
// Blocks [0, B*H): row grams (pixels of row i). Blocks [B*H, B*H+B*W): col grams.
__global__ __launch_bounds__(256)
void criss_cross_gram_kernel(const float* __restrict__ x, float* __restrict__ out) {
    __shared__ unsigned short xs[128 * LDS_STRIDE];       // 18432 B
    __shared__ float ep[4][16 * EP_STRIDE];               // 33280 B

    const int g = blockIdx.x;
    const bool isCol = (g >= BB * HH);
    const int gg = isCol ? (g - BB * HH) : g;
    const int b = gg >> 7;       // / 128
    const int p = gg & 127;      // i (row gram) or j (col gram)

    const float* xbase;
    int xRowStride;      // floats between consecutive X rows
    int outBase;         // float offset of G-row 0 in out
    int outRowStride;    // floats between consecutive G rows in out
    if (!isCol) {
        xbase        = x + ((b * HH + p) * WW) * CC;   // x[b,p,0,:]
        xRowStride   = CC;                              // row pixels contiguous
        outBase      = ((b * HH + p) * WW) * OUTW;      // out[b,p,j,*]
        outRowStride = OUTW;
    } else {
        xbase        = x + (b * HH * WW + p) * CC;      // x[b,0,p,:]
        xRowStride   = WW * CC;                         // column pixels strided
        outBase      = (b * HH * WW + p) * OUTW;        // out[b,i,p,127+*]
        outRowStride = WW * OUTW;
    }

    const int t = threadIdx.x;

    // ---- Stage X (128x64 fp32) into LDS as bf16. 2048 float4 loads total. ----
    #pragma unroll
    for (int r = 0; r < 8; ++r) {
        const int idx = r * 256 + t;        // 0..2047
        const int row = idx >> 4;           // 0..127
        const int c4  = (idx & 15) << 2;    // float4 column
        const float4 v = *(const float4*)(xbase + row * xRowStride + c4);
        ushort4* dst = (ushort4*)&xs[row * LDS_STRIDE + c4];
        *dst = make_ushort4(f2bf(v.x), f2bf(v.y), f2bf(v.z), f2bf(v.w));
    }
    __syncthreads();

    // ---- MFMA: wave w computes G rows [w*32, w*32+32) x all 128 cols. ----
    const int wave = t >> 6;
    const int lane = t & 63;
    const int m16  = lane & 15;
    const int quad = lane >> 4;

    f32x4 acc[2][8];
    #pragma unroll
    for (int rt = 0; rt < 2; ++rt)
        #pragma unroll
        for (int ct = 0; ct < 8; ++ct)
            acc[rt][ct] = (f32x4){0.f, 0.f, 0.f, 0.f};

    #pragma unroll
    for (int ks = 0; ks < 2; ++ks) {
        const int kOff = ks * 32 + quad * 8;
        bf16x8 afrag[2];
        #pragma unroll
        for (int rt = 0; rt < 2; ++rt) {
            const int row = wave * 32 + rt * 16 + m16;
            afrag[rt] = *(const bf16x8*)&xs[row * LDS_STRIDE + kOff];
        }
        #pragma unroll
        for (int ct = 0; ct < 8; ++ct) {
            const int row = ct * 16 + m16;
            const bf16x8 bfrag = *(const bf16x8*)&xs[row * LDS_STRIDE + kOff];
            acc[0][ct] = __builtin_amdgcn_mfma_f32_16x16x32_bf16(afrag[0], bfrag, acc[0][ct], 0, 0, 0);
            acc[1][ct] = __builtin_amdgcn_mfma_f32_16x16x32_bf16(afrag[1], bfrag, acc[1][ct], 0, 0, 0);
        }
    }

    // ---- Epilogue: per-wave LDS round-trip, then contiguous 256B stores. ----
    // C/D layout: col = lane&15, row = quad*4 + reg.
    float* myep = &ep[wave][0];
    const int width = isCol ? 128 : 127;   // floats per output-row segment
    const int gOffs = isCol ? 127 : 0;     // segment offset within output row

    #pragma unroll
    for (int rt = 0; rt < 2; ++rt) {
        const int rowBase = wave * 32 + rt * 16;

        // Scatter C fragments into LDS, applying diagonal compaction here
        // (cheap LDS predication instead of predicated global stores).
        #pragma unroll
        for (int ct = 0; ct < 8; ++ct) {
            #pragma unroll
            for (int reg = 0; reg < 4; ++reg) {
                const int rl = quad * 4 + reg;      // local row 0..15
                const int gm = rowBase + rl;
                const int gn = ct * 16 + m16;
                const float v = acc[rt][ct][reg];
                if (isCol) {
                    myep[rl * EP_STRIDE + gn] = v;
                } else if (gn != gm) {
                    myep[rl * EP_STRIDE + (gn - (gn > gm ? 1 : 0))] = v;
                }
            }
        }
        __syncthreads();   // uniform across all waves; orders LDS write->read

        // Linear read-back + contiguous global stores: 2 x 256B per G-row.
        #pragma unroll
        for (int r = 0; r < 16; ++r) {
            float* rp = out + outBase + (rowBase + r) * outRowStride + gOffs;
            rp[lane] = myep[r * EP_STRIDE + lane];
            if (lane < width - 64)
                rp[64 + lane] = myep[r * EP_STRIDE + 64 + lane];
        }
    }
}

extern "C" void kernel_launch(void* const* d_in, const int* in_sizes, int n_in,
                              void* d_out, int out_size, void* d_ws, size_t ws_size,
                              hipStream_t stream) {
    const float* x = (const float*)d_in[0];
    float* out = (float*)d_out;
    // 1024 row-gram blocks + 1024 col-gram blocks, one 128x128 Gram each.
    criss_cross_gram_kernel<<<dim3(BB * HH + BB * WW), dim3(256), 0, stream>>>(x, out);
}